// Round 4
// baseline (11001.465 us; speedup 1.0000x reference)
//
#include <hip/hip_runtime.h>

#define N_USERS 100000
#define N_ITEMS 200000
#define N_NODES 300000
#define EMB 64
#define NNZ_C 9600000

#define RPB 192                                  // rows per bucket
#define NB ((N_NODES + RPB - 1) / RPB)           // 1563 buckets
#define ASTRIDE 65                               // LDS acc row stride (bank-conflict break)
#define COL_BITS 19
#define COL_MASK 0x7FFFFu
#define TILE 8192
#define NTILES ((NNZ_C + TILE - 1) / TILE)       // 1172
#define SCAN_ENT ((NB + 255) / 256)              // 7

// ==================== tiny utility ====================

__global__ void zero_int_kernel(int* __restrict__ p, int n) {
    int i = blockIdx.x * blockDim.x + threadIdx.x;
    if (i < n) p[i] = 0;
}

// ==================== bucket histogram (LDS-privatized) ====================

__global__ void bucket_hist_kernel(const int* __restrict__ rows, int* __restrict__ counts) {
    __shared__ int h[NB];
    for (int i = threadIdx.x; i < NB; i += blockDim.x) h[i] = 0;
    __syncthreads();
    int stride = gridDim.x * blockDim.x;
    for (int e = blockIdx.x * blockDim.x + threadIdx.x; e < NNZ_C; e += stride)
        atomicAdd(&h[rows[e] / RPB], 1);
    __syncthreads();
    for (int i = threadIdx.x; i < NB; i += blockDim.x)
        if (h[i]) atomicAdd(&counts[i], h[i]);
}

// ==================== exclusive scan of NB bucket counts (1 block) ====================

__global__ void bucket_scan_kernel(const int* __restrict__ counts, int* __restrict__ bucket_ptr,
                                   int* __restrict__ cursor16) {
    __shared__ int part[256];
    int t = threadIdx.x;
    int loc[SCAN_ENT];
    int s = 0;
    int base = t * SCAN_ENT;
    for (int i = 0; i < SCAN_ENT; ++i) {
        int idx = base + i;
        int v = (idx < NB) ? counts[idx] : 0;
        loc[i] = s;
        s += v;
    }
    part[t] = s;
    __syncthreads();
    for (int off = 1; off < 256; off <<= 1) {
        int x = (t >= off) ? part[t - off] : 0;
        __syncthreads();
        part[t] += x;
        __syncthreads();
    }
    int pre = (t > 0) ? part[t - 1] : 0;
    for (int i = 0; i < SCAN_ENT; ++i) {
        int idx = base + i;
        if (idx < NB) {
            int p = pre + loc[i];
            bucket_ptr[idx] = p;
            cursor16[idx * 16] = p;      // padded cursor: 1 per 64B line
        }
    }
    if (t == 0) bucket_ptr[NB] = NNZ_C;
}

// ==================== pass A: tiled multisplit scatter into bucket order ====================
// per 8192-edge tile: LDS hist -> ONE fetch-add per (tile,bucket) -> ranked scatter.
// contiguous ~4-6 edge runs per bucket per tile -> low write amplification;
// cursor contention: ~1.8M atomics spread over 1563 padded lines.
__global__ void passA_kernel(const int* __restrict__ rows, const int* __restrict__ cols,
                             const float* __restrict__ vals, int* __restrict__ cursor16,
                             uint2* __restrict__ binbuf) {
    __shared__ int lh[NB];     // tile histogram, then reused as rank cursor
    __shared__ int gb[NB];     // global base per bucket for this tile
    int t = threadIdx.x;
    int base = blockIdx.x * TILE;
    for (int i = t; i < NB; i += 256) lh[i] = 0;
    __syncthreads();

    int myr[TILE / 256];       // cache rows in regs (32 VGPRs)
    for (int k = 0; k < TILE / 256; ++k) {
        int e = base + t + k * 256;
        if (e < NNZ_C) {
            int r = rows[e];
            myr[k] = r;
            atomicAdd(&lh[r / RPB], 1);
        } else myr[k] = -1;
    }
    __syncthreads();

    for (int bb = t; bb < NB; bb += 256) {
        int c = lh[bb];
        gb[bb] = c ? atomicAdd(&cursor16[bb * 16], c) : 0;
        lh[bb] = 0;            // becomes local rank counter
    }
    __syncthreads();

    for (int k = 0; k < TILE / 256; ++k) {
        int e = base + t + k * 256;
        if (e < NNZ_C) {
            int r = myr[k];
            int b = r / RPB;
            int rk = atomicAdd(&lh[b], 1);
            unsigned packed = ((unsigned)(r - b * RPB) << COL_BITS) | (unsigned)cols[e];
            binbuf[gb[b] + rk] = make_uint2(packed, __float_as_uint(vals[e]));
        }
    }
}

// ==================== bucketed SpMM: LDS accumulator, no global atomics ====================
// one block per bucket; 512 thr = 32 sixteen-lane groups; group handles one edge:
// 16 lanes x float4 = coalesced 256B gather, 4x ds_add_f32 into sacc.
__launch_bounds__(512)
__global__ void spmm_bucket_kernel(const int* __restrict__ bucket_ptr, const uint2* __restrict__ binbuf,
                                   const float4* __restrict__ gu, const float4* __restrict__ gi,
                                   int split,
                                   float4* __restrict__ ego_out, float4* __restrict__ acc,
                                   float scale, int write_ego, int init_acc) {
    __shared__ float sacc[RPB * ASTRIDE];        // 49,920 B -> 3 blocks/CU
    int b = blockIdx.x;
    int t = threadIdx.x;
    for (int i = t; i < RPB * ASTRIDE; i += 512) sacc[i] = 0.f;
    int beg = bucket_ptr[b], end = bucket_ptr[b + 1];
    int g = t >> 4, lane = t & 15;
    __syncthreads();

#define EDGE(eidx)                                                                 \
    {                                                                              \
        uint2 p = binbuf[eidx];                                                    \
        int col = (int)(p.x & COL_MASK);                                           \
        int rl  = (int)(p.x >> COL_BITS);                                          \
        float v = __uint_as_float(p.y);                                            \
        float4 x = (col < split) ? gu[col * 16 + lane] : gi[(col - split) * 16 + lane]; \
        int o = rl * ASTRIDE + lane * 4;                                           \
        atomicAdd(&sacc[o],     v * x.x);                                          \
        atomicAdd(&sacc[o + 1], v * x.y);                                          \
        atomicAdd(&sacc[o + 2], v * x.z);                                          \
        atomicAdd(&sacc[o + 3], v * x.w);                                          \
    }

    int e = beg + g;
    for (; e + 96 < end; e += 128) {             // 4 gathers in flight per group
        uint2 p0 = binbuf[e], p1 = binbuf[e + 32], p2 = binbuf[e + 64], p3 = binbuf[e + 96];
        int c0 = (int)(p0.x & COL_MASK), c1 = (int)(p1.x & COL_MASK);
        int c2 = (int)(p2.x & COL_MASK), c3 = (int)(p3.x & COL_MASK);
        float4 x0 = (c0 < split) ? gu[c0 * 16 + lane] : gi[(c0 - split) * 16 + lane];
        float4 x1 = (c1 < split) ? gu[c1 * 16 + lane] : gi[(c1 - split) * 16 + lane];
        float4 x2 = (c2 < split) ? gu[c2 * 16 + lane] : gi[(c2 - split) * 16 + lane];
        float4 x3 = (c3 < split) ? gu[c3 * 16 + lane] : gi[(c3 - split) * 16 + lane];
        int r0 = (int)(p0.x >> COL_BITS), r1 = (int)(p1.x >> COL_BITS);
        int r2 = (int)(p2.x >> COL_BITS), r3 = (int)(p3.x >> COL_BITS);
        float v0 = __uint_as_float(p0.y), v1 = __uint_as_float(p1.y);
        float v2 = __uint_as_float(p2.y), v3 = __uint_as_float(p3.y);
        int o0 = r0 * ASTRIDE + lane * 4, o1 = r1 * ASTRIDE + lane * 4;
        int o2 = r2 * ASTRIDE + lane * 4, o3 = r3 * ASTRIDE + lane * 4;
        atomicAdd(&sacc[o0], v0 * x0.x); atomicAdd(&sacc[o0 + 1], v0 * x0.y);
        atomicAdd(&sacc[o0 + 2], v0 * x0.z); atomicAdd(&sacc[o0 + 3], v0 * x0.w);
        atomicAdd(&sacc[o1], v1 * x1.x); atomicAdd(&sacc[o1 + 1], v1 * x1.y);
        atomicAdd(&sacc[o1 + 2], v1 * x1.z); atomicAdd(&sacc[o1 + 3], v1 * x1.w);
        atomicAdd(&sacc[o2], v2 * x2.x); atomicAdd(&sacc[o2 + 1], v2 * x2.y);
        atomicAdd(&sacc[o2 + 2], v2 * x2.z); atomicAdd(&sacc[o2 + 3], v2 * x2.w);
        atomicAdd(&sacc[o3], v3 * x3.x); atomicAdd(&sacc[o3 + 1], v3 * x3.y);
        atomicAdd(&sacc[o3 + 2], v3 * x3.z); atomicAdd(&sacc[o3 + 3], v3 * x3.w);
    }
    for (; e < end; e += 32) EDGE(e);
#undef EDGE
    __syncthreads();

    // epilogue: write bucket rows once; fused acc update (+ optional ego_out)
    int r0 = t >> 4;                              // 0..31
    for (int k = 0; k < RPB; k += 32) {
        int rl = r0 + k;
        int r = b * RPB + rl;
        if (r < N_NODES) {
            int o = rl * ASTRIDE + lane * 4;
            float4 s = make_float4(sacc[o], sacc[o + 1], sacc[o + 2], sacc[o + 3]);
            int go = r * 16 + lane;
            float4 a;
            if (init_acc) a = (r < N_USERS) ? gu[r * 16 + lane] : gi[(r - N_USERS) * 16 + lane];
            else          a = acc[go];
            a.x = (a.x + s.x) * scale;
            a.y = (a.y + s.y) * scale;
            a.z = (a.z + s.z) * scale;
            a.w = (a.w + s.w) * scale;
            acc[go] = a;
            if (write_ego) ego_out[go] = s;
        }
    }
}

// ==================== fallback (round-1 atomic path) ====================

__global__ void init_kernel(const float4* __restrict__ ue, const float4* __restrict__ ie,
                            float4* __restrict__ ego, float4* __restrict__ acc) {
    const int user4 = N_USERS * EMB / 4;
    const int total4 = N_NODES * EMB / 4;
    int stride = gridDim.x * blockDim.x;
    for (int i = blockIdx.x * blockDim.x + threadIdx.x; i < total4; i += stride) {
        float4 v = (i < user4) ? ue[i] : ie[i - user4];
        ego[i] = v;
        acc[i] = v;
    }
}

__global__ void zero4_kernel(float4* __restrict__ p, int n4) {
    int stride = gridDim.x * blockDim.x;
    float4 z = make_float4(0.f, 0.f, 0.f, 0.f);
    for (int i = blockIdx.x * blockDim.x + threadIdx.x; i < n4; i += stride) p[i] = z;
}

__global__ void spmm_atomic_kernel(const int* __restrict__ rows, const int* __restrict__ cols,
                                   const float* __restrict__ vals,
                                   const float* __restrict__ ego_in, float* __restrict__ ego_out) {
    int wave = (blockIdx.x * blockDim.x + threadIdx.x) >> 6;
    int lane = threadIdx.x & 63;
    int nwaves = (gridDim.x * blockDim.x) >> 6;
    for (int e = wave; e < NNZ_C; e += nwaves) {
        int r = rows[e];
        int c = cols[e];
        float v = vals[e];
        float x = ego_in[c * EMB + lane];
        atomicAdd(&ego_out[r * EMB + lane], v * x);
    }
}

__global__ void add_kernel(float4* __restrict__ acc, const float4* __restrict__ ego,
                           float scale, int n4) {
    int stride = gridDim.x * blockDim.x;
    for (int i = blockIdx.x * blockDim.x + threadIdx.x; i < n4; i += stride) {
        float4 a = acc[i];
        float4 g = ego[i];
        a.x = (a.x + g.x) * scale;
        a.y = (a.y + g.y) * scale;
        a.z = (a.z + g.z) * scale;
        a.w = (a.w + g.w) * scale;
        acc[i] = a;
    }
}

// ==================== launch ====================

extern "C" void kernel_launch(void* const* d_in, const int* in_sizes, int n_in,
                              void* d_out, int out_size, void* d_ws, size_t ws_size,
                              hipStream_t stream) {
    const float* user_emb = (const float*)d_in[0];
    const float* item_emb = (const float*)d_in[1];
    const int*   adj_rows = (const int*)d_in[2];
    const int*   adj_cols = (const int*)d_in[3];
    const float* adj_vals = (const float*)d_in[4];
    float* acc = (float*)d_out;

    const size_t egoN = (size_t)N_NODES * EMB;            // 19.2M floats = 76.8 MB
    float* ego_a = (float*)d_ws;
    float* ego_b = ego_a + egoN;
    uint2* binbuf     = (uint2*)(ego_b + egoN);           // NNZ * 8B = 76.8 MB
    int*   bucket_ptr = (int*)(binbuf + (size_t)NNZ_C);   // NB+1
    int*   counts     = bucket_ptr + NB + 1;              // NB
    int*   cursor16   = counts + NB;                      // NB*16 (padded cursors)
    size_t needed = (size_t)((char*)(cursor16 + (size_t)NB * 16) - (char*)d_ws);

    const int total4 = N_NODES * EMB / 4;

    if (ws_size >= needed) {
        // ---- bucket-sort edge list (bucket granularity only) ----
        zero_int_kernel<<<(NB + 255) / 256, 256, 0, stream>>>(counts, NB);
        bucket_hist_kernel<<<256, 256, 0, stream>>>(adj_rows, counts);
        bucket_scan_kernel<<<1, 256, 0, stream>>>(counts, bucket_ptr, cursor16);
        passA_kernel<<<NTILES, 256, 0, stream>>>(adj_rows, adj_cols, adj_vals, cursor16, binbuf);

        // ---- propagate: bucketed SpMM with LDS accumulation ----
        // L1: inputs -> ego_b, acc = ego0 + s
        spmm_bucket_kernel<<<NB, 512, 0, stream>>>(bucket_ptr, binbuf,
            (const float4*)user_emb, (const float4*)item_emb, N_USERS,
            (float4*)ego_b, (float4*)acc, 1.0f, 1, 1);
        // L2: ego_b -> ego_a, acc += s
        spmm_bucket_kernel<<<NB, 512, 0, stream>>>(bucket_ptr, binbuf,
            (const float4*)ego_b, (const float4*)ego_b, N_NODES,
            (float4*)ego_a, (float4*)acc, 1.0f, 1, 0);
        // L3: ego_a -> none, acc = (acc + s) * 0.25
        spmm_bucket_kernel<<<NB, 512, 0, stream>>>(bucket_ptr, binbuf,
            (const float4*)ego_a, (const float4*)ego_a, N_NODES,
            (float4*)ego_b, (float4*)acc, 0.25f, 0, 0);
    } else {
        // ---- fallback: atomic COO path ----
        init_kernel<<<4096, 256, 0, stream>>>(
            (const float4*)user_emb, (const float4*)item_emb,
            (float4*)ego_a, (float4*)acc);
        float* ego_in = ego_a;
        float* ego_out = ego_b;
        for (int layer = 0; layer < 3; ++layer) {
            zero4_kernel<<<4096, 256, 0, stream>>>((float4*)ego_out, total4);
            spmm_atomic_kernel<<<4096, 256, 0, stream>>>(
                adj_rows, adj_cols, adj_vals, ego_in, ego_out);
            float scale = (layer == 2) ? 0.25f : 1.0f;
            add_kernel<<<4096, 256, 0, stream>>>(
                (float4*)acc, (const float4*)ego_out, scale, total4);
            float* t = ego_in; ego_in = ego_out; ego_out = t;
        }
    }
}